// Round 10
// baseline (172.417 us; speedup 1.0000x reference)
//
#include <hip/hip_runtime.h>

// Problem constants (match reference)
#define B_ 64
#define T_ 4096
#define C_ 8
#define K_ 150

constexpr int TPB    = 256;   // 16 waves/CU: R7 proved 32 waves/CU => L2 RMW storm
constexpr int TCHUNK = 256;   // timesteps per block
constexpr int TWAVE  = 64;    // timesteps per wave (round-robin pairs, R10)
constexpr int NACC   = 27;    // 24 num (3k x 8c) + 3 den per lane
constexpr int RED_ST = 29;    // red64 stride: gcd(29,32)=1 -> conflict-free
constexpr int NBLK   = B_ * (T_ / TCHUNK);   // 1024 main blocks
constexpr int WSSTR  = NACC * 64;            // 1728 floats per block partial

#if __has_builtin(__builtin_amdgcn_exp2f)
#define EXP2F(x) __builtin_amdgcn_exp2f(x)
#else
#define EXP2F(x) __expf((x) * 0.6931471805599453f)
#endif

typedef float v2f __attribute__((ext_vector_type(2)));

// Packed dual-FMA: d = a*b + c on both halves of a VGPR pair (v_pk_fma_f32).
__device__ __forceinline__ v2f pk_fma(v2f a, v2f b, v2f c) {
    v2f d;
    asm("v_pk_fma_f32 %0, %1, %2, %3" : "=v"(d) : "v"(a), "v"(b), "v"(c));
    return d;
}

// One DPP reduce step: v += dpp_shifted(v). Pure VALU (no LDS pipe, no waitcnt).
template <int CTRL>
__device__ __forceinline__ float dpp_add(float v) {
    int sh = __builtin_amdgcn_update_dpp(0, __float_as_int(v), CTRL, 0xf, 0xf, true);
    return v + __int_as_float(sh);
}

// DUAL wave64 sum: two independent reductions, interleaved (kept from R9;
// neutral but harmless, and pairs naturally with the 2-row body).
__device__ __forceinline__ void wave_sum64x2(float& a, float& b) {
    a = dpp_add<0x111>(a);  b = dpp_add<0x111>(b);   // row_shr:1
    a = dpp_add<0x112>(a);  b = dpp_add<0x112>(b);   // row_shr:2
    a = dpp_add<0x114>(a);  b = dpp_add<0x114>(b);   // row_shr:4
    a = dpp_add<0x118>(a);  b = dpp_add<0x118>(b);   // row_shr:8
    a = dpp_add<0x142>(a);  b = dpp_add<0x142>(b);   // row_bcast:15
    a = dpp_add<0x143>(a);  b = dpp_add<0x143>(b);   // row_bcast:31
    a = __int_as_float(__builtin_amdgcn_readlane(__float_as_int(a), 63));
    b = __int_as_float(__builtin_amdgcn_readlane(__float_as_int(b), 63));
}

// ---- fallback (atomic) path helpers ----------------------------------------
__global__ void zero_accum(float* __restrict__ patch, float* __restrict__ den_g) {
    int i = blockIdx.x * blockDim.x + threadIdx.x;
    int n_patch = B_ * K_ * C_;           // 76800
    int n_total = n_patch + B_ * K_;      // +9600
    if (i < n_patch)      patch[i] = 0.0f;
    else if (i < n_total) den_g[i - n_patch] = 0.0f;
}

__global__ void finalize_patch(float* __restrict__ patch, const float* __restrict__ den_g) {
    int i = blockIdx.x * blockDim.x + threadIdx.x;
    if (i < B_ * K_ * C_) patch[i] = patch[i] / (den_g[i / C_] + 1e-8f);
}

// ---- main kernel ------------------------------------------------------------
// R10: WRITE-FRONT DENSIFICATION. Every prior variant gave each wave a private
// 64-row (38.4 KB) range -> 4096 simultaneous write fronts device-wide, spaced
// 38 KB apart (HBM page thrash). The harness fill (6.7 TB/s) writes ONE dense
// front. Change: round-robin row ownership — wave w owns row-pairs {8i+2w,
// 8i+2w+1}, so each block advances one dense ~4.8 KB front (256 fronts
// device-wide, 16x fewer). Accumulation is row-order-independent; reduction
// and LDS broadcast reads unchanged.
// Falsified: VALU issue (R3), store pattern (R4), NT stores (R2), fence (R8),
// occupancy up (R7: RMW storm), occupancy caps (R5/R6), intra-wave ILP (R9).
template <bool USE_WS>
__global__ __launch_bounds__(TPB, 4) void softkmeans_main(
        const float* __restrict__ x,        // [B,T,C]
        const float* __restrict__ cent,     // [K,C]
        float* __restrict__ assign_out,     // [B,T,K]
        float* __restrict__ num_g,          // atomic path: [B,K,C] (in d_out)
        float* __restrict__ den_g,          // atomic path: [B,K]   (in d_ws)
        float* __restrict__ ws) {           // ws path: [NBLK][NACC][64]
    __shared__ float4 xt[TCHUNK * 2];       // 8 KB: x tile, [t][c] as 2x float4
    __shared__ float  red64[64][RED_ST];    // 7.4 KB: serialized wave reduction

    const int bx    = blockIdx.x;
    const int b     = bx >> 4;             // 16 chunks per batch
    const int chunk = bx & 15;
    const int t0    = chunk * TCHUNK;
    const int tid   = threadIdx.x;
    const int wave  = tid >> 6;
    const int lane  = tid & 63;

    // Stage x tile: 2048 contiguous floats, fully coalesced float4 loads.
    const float4* xsrc = (const float4*)(x + ((size_t)b * T_ + t0) * C_);
    xt[tid]       = xsrc[tid];
    xt[tid + TPB] = xsrc[tid + TPB];

    // Centroid fragments in registers: lane owns k in {lane, lane+64, lane+128}.
    // Fold 2*log2(e) into cen and log2(e) into csq so the logit is already in
    // exp2 domain: e = exp2(dot(cen2,x) - csq2), starting the FMA chain at -csq2.
    const float LOG2E = 1.4426950408889634f;
    v2f  cen2[3][4];
    float csq[3];
#pragma unroll
    for (int j = 0; j < 3; ++j) {
        int k = lane + 64 * j;
        if (k < K_) {
            float s = 0.0f;
#pragma unroll
            for (int c = 0; c < C_; ++c) {
                float v = cent[k * C_ + c];
                cen2[j][c / 2][c & 1] = 2.0f * LOG2E * v;
                s += v * v;
            }
            csq[j] = LOG2E * s;
        } else {
            // exp2(-1e30) = 0: dead lane contributes nothing
#pragma unroll
            for (int p = 0; p < 4; ++p) cen2[j][p] = v2f{0.0f, 0.0f};
            csq[j] = 1e30f;
        }
    }

    v2f  num2[3][4] = {};
    float den[3] = {0.0f, 0.0f, 0.0f};

    __syncthreads();

    // R10 row mapping: iteration ii handles rows r0 = 8*ii + 2*wave, r0+1
    // (relative to chunk). All 4 waves' rows at a given ii are adjacent ->
    // dense 4.8 KB block-level write front moving sequentially.
    const unsigned chunk_base = ((unsigned)(b * T_) + (unsigned)t0) * K_ + (unsigned)lane;

#pragma unroll 2
    for (int ii = 0; ii < TWAVE / 2; ++ii) {
        const int r0 = 8 * ii + 2 * wave;       // row within chunk
        // Broadcast LDS reads for both rows (wave-uniform addr -> conflict-free).
        float4 xa0 = xt[r0 * 2],     xa1 = xt[r0 * 2 + 1];
        float4 xb0 = xt[r0 * 2 + 2], xb1 = xt[r0 * 2 + 3];
        v2f xa[4] = {v2f{xa0.x, xa0.y}, v2f{xa0.z, xa0.w},
                     v2f{xa1.x, xa1.y}, v2f{xa1.z, xa1.w}};
        v2f xb[4] = {v2f{xb0.x, xb0.y}, v2f{xb0.z, xb0.w},
                     v2f{xb1.x, xb1.y}, v2f{xb1.z, xb1.w}};

        // Two independent logit/exp chains (rows r0, r0+1), interleaved.
        float ea[3], eb[3];
#pragma unroll
        for (int j = 0; j < 3; ++j) {
            v2f da = pk_fma(cen2[j][0], xa[0], v2f{-csq[j], 0.0f});
            v2f db = pk_fma(cen2[j][0], xb[0], v2f{-csq[j], 0.0f});
            da = pk_fma(cen2[j][1], xa[1], da);
            db = pk_fma(cen2[j][1], xb[1], db);
            da = pk_fma(cen2[j][2], xa[2], da);
            db = pk_fma(cen2[j][2], xb[2], db);
            da = pk_fma(cen2[j][3], xa[3], da);
            db = pk_fma(cen2[j][3], xb[3], db);
            ea[j] = EXP2F(da.x + da.y);
            eb[j] = EXP2F(db.x + db.y);
        }

        // Dual wave-wide sums (interleaved DPP trees). Dead lanes hold 0.
        float sa = ea[0] + ea[1] + ea[2];
        float sb = eb[0] + eb[1] + eb[2];
        wave_sum64x2(sa, sb);
        float inva = __builtin_amdgcn_rcpf(sa);  // rel err ~1e-7 vs 2.4e-3 tol
        float invb = __builtin_amdgcn_rcpf(sb);

        float a0 = ea[0] * inva, a1 = ea[1] * inva, a2 = ea[2] * inva;
        float b0 = eb[0] * invb, b1 = eb[1] * invb, b2 = eb[2] * invb;

        // Plain cached stores (R2/R4/R8 lessons: cached, any width, no fence).
        unsigned basea = chunk_base + (unsigned)(r0 * K_);
        unsigned baseb = basea + (unsigned)K_;
        assign_out[basea]      = a0;
        assign_out[baseb]      = b0;
        assign_out[basea + 64] = a1;
        assign_out[baseb + 64] = b1;
        if (lane < K_ - 128) {
            assign_out[basea + 128] = a2;
            assign_out[baseb + 128] = b2;
        }

        den[0] += a0 + b0; den[1] += a1 + b1; den[2] += a2 + b2;
        v2f a02 = v2f{a0, a0}, a12 = v2f{a1, a1}, a22 = v2f{a2, a2};
        v2f b02 = v2f{b0, b0}, b12 = v2f{b1, b1}, b22 = v2f{b2, b2};
#pragma unroll
        for (int p = 0; p < 4; ++p) {
            num2[0][p] = pk_fma(a02, xa[p], num2[0][p]);
            num2[1][p] = pk_fma(a12, xa[p], num2[1][p]);
            num2[2][p] = pk_fma(a22, xa[p], num2[2][p]);
            num2[0][p] = pk_fma(b02, xb[p], num2[0][p]);
            num2[1][p] = pk_fma(b12, xb[p], num2[1][p]);
            num2[2][p] = pk_fma(b22, xb[p], num2[2][p]);
        }
    }

    // Cross-wave reduction, serialized into red64[64][29] (7.4 KB):
    // wave 0 writes, waves 1-2 add, wave 3 adds in-register and emits.
    // Row->wave assignment is irrelevant here (sum over all rows).
    float mine[NACC];
#pragma unroll
    for (int j = 0; j < 3; ++j) {
#pragma unroll
        for (int p = 0; p < 4; ++p) {
            mine[j * C_ + 2 * p]     = num2[j][p].x;
            mine[j * C_ + 2 * p + 1] = num2[j][p].y;
        }
        mine[24 + j] = den[j];
    }

    if (wave == 0) {
#pragma unroll
        for (int i = 0; i < NACC; ++i) red64[lane][i] = mine[i];
    }
    __syncthreads();
    if (wave == 1) {
#pragma unroll
        for (int i = 0; i < NACC; ++i) red64[lane][i] += mine[i];
    }
    __syncthreads();
    if (wave == 2) {
#pragma unroll
        for (int i = 0; i < NACC; ++i) red64[lane][i] += mine[i];
    }
    __syncthreads();

    if (wave == 3) {
        float acc[NACC];
#pragma unroll
        for (int i = 0; i < NACC; ++i) acc[i] = red64[lane][i] + mine[i];

        if constexpr (USE_WS) {
            // Per-block partial tile, coalesced: ws[bx][i][lane]. No fence, no
            // flags — finalize_ws is a separate kernel (stream-ordered).
            float* dst = ws + (size_t)bx * WSSTR + lane;
#pragma unroll
            for (int i = 0; i < NACC; ++i) dst[i * 64] = acc[i];
        } else {
#pragma unroll
            for (int j = 0; j < 3; ++j) {
                int k = lane + 64 * j;
                if (k < K_) {
#pragma unroll
                    for (int c = 0; c < C_; ++c)
                        atomicAdd(&num_g[((size_t)b * K_ + k) * C_ + c], acc[j * C_ + c]);
                    atomicAdd(&den_g[b * K_ + k], acc[24 + j]);
                }
            }
        }
    }
}

// Reduce the 16 chunk-partials per (b,k,c) and divide by den.
// Grid: B_*3 blocks (one per (b,j)), 512 threads: c = tid>>6 in [0,8), lane = k-64j.
__global__ __launch_bounds__(512) void finalize_ws(
        const float* __restrict__ ws,       // [NBLK][NACC][64]
        float* __restrict__ patch) {        // [B,K,C]
    __shared__ float dsh[64];
    const int b    = blockIdx.x / 3;
    const int j    = blockIdx.x % 3;
    const int c    = threadIdx.x >> 6;
    const int lane = threadIdx.x & 63;
    const int k    = lane + 64 * j;

    // num partial sum over 16 chunks (reads coalesced: lane is fastest dim).
    const float* src = ws + (size_t)(b * 16) * WSSTR + lane;
    float s = 0.0f;
#pragma unroll
    for (int ch = 0; ch < 16; ++ch)
        s += src[ch * WSSTR + (j * C_ + c) * 64];

    // den partial sum, computed once by wave 0 (c==0), shared via LDS.
    if (c == 0) {
        float d = 0.0f;
#pragma unroll
        for (int ch = 0; ch < 16; ++ch)
            d += src[ch * WSSTR + (24 + j) * 64];
        dsh[lane] = d;
    }
    __syncthreads();

    if (k < K_)
        patch[((size_t)b * K_ + k) * C_ + c] = s / (dsh[lane] + 1e-8f);
}

extern "C" void kernel_launch(void* const* d_in, const int* in_sizes, int n_in,
                              void* d_out, int out_size, void* d_ws, size_t ws_size,
                              hipStream_t stream) {
    const float* x    = (const float*)d_in[0];   // [B,T,C]
    const float* cent = (const float*)d_in[1];   // [K,C]

    float* out        = (float*)d_out;
    float* patch      = out;                           // [B,K,C] = 76800 floats
    float* assign_out = out + (size_t)B_ * K_ * C_;    // [B,T,K]

    const size_t ws_need = (size_t)NBLK * WSSTR * sizeof(float);  // 7.08 MB

    if (ws_size >= ws_need) {
        // No-atomic path: per-block partials in d_ws, then one reduce kernel.
        float* ws = (float*)d_ws;
        softkmeans_main<true><<<NBLK, TPB, 0, stream>>>(
            x, cent, assign_out, nullptr, nullptr, ws);
        finalize_ws<<<B_ * 3, 512, 0, stream>>>(ws, patch);
    } else {
        // Fallback: verified atomic path (zero -> main(atomic) -> finalize).
        float* den_g = (float*)d_ws;                   // [B,K] = 38.4 KB
        int nz = B_ * K_ * C_ + B_ * K_;
        zero_accum<<<(nz + TPB - 1) / TPB, TPB, 0, stream>>>(patch, den_g);
        softkmeans_main<false><<<NBLK, TPB, 0, stream>>>(
            x, cent, assign_out, patch, den_g, nullptr);
        int np = B_ * K_ * C_;
        finalize_patch<<<(np + TPB - 1) / TPB, TPB, 0, stream>>>(patch, den_g);
    }
}